// Round 12
// baseline (331.287 us; speedup 1.0000x reference)
//
#include <hip/hip_runtime.h>
#include <hip/hip_fp16.h>
#include <cmath>

typedef _Float16 half8 __attribute__((ext_vector_type(8)));
typedef _Float16 h2 __attribute__((ext_vector_type(2)));
typedef float f32x4 __attribute__((ext_vector_type(4)));

#define BINCAP 2600              // mean edges/bin ~2176, +9 sigma guard
#define BSTRIDE (BINCAP + 384)   // room for per-dst pad-to-4 (128 dst x 3)
#define NBINS_MAX 512            // N<=65536 (16-bit src pack also requires this)

// DPP cross-lane adds within quads (VALU pipe, no LDS): t += t[lane^mask]
__device__ __forceinline__ float dpp_add_xor1(float t) {
    int r = __builtin_amdgcn_update_dpp(0, __float_as_int(t), 0xB1, 0xF, 0xF, true);
    return t + __int_as_float(r);
}
__device__ __forceinline__ float dpp_add_xor2(float t) {
    int r = __builtin_amdgcn_update_dpp(0, __float_as_int(t), 0x4E, 0xF, 0xF, true);
    return t + __int_as_float(r);
}

__device__ __forceinline__ float hdot2(h2 a, h2 b, float acc) {
#if __has_builtin(__builtin_amdgcn_fdot2)
    return __builtin_amdgcn_fdot2(a, b, acc, false);
#else
    return acc + (float)a[0] * (float)b[0] + (float)a[1] * (float)b[1];
#endif
}

// ---------------- CSR build, phase 1: bin by dst>>7 (block-exclusive segments) ----------------
__global__ __launch_bounds__(256) void bin_edges(const int* __restrict__ src,
                                                 const int* __restrict__ dst,
                                                 int* __restrict__ binCnt,
                                                 unsigned* __restrict__ binned,
                                                 int E, int nbins)
{
    __shared__ int hist[NBINS_MAX];
    __shared__ int ofs[NBINS_MAX];
    int tid = threadIdx.x;
    for (int i = tid; i < nbins; i += 256) hist[i] = 0;
    __syncthreads();
    int chunk = (E + gridDim.x - 1) / gridDim.x;
    int e0 = blockIdx.x * chunk;
    int e1 = min(e0 + chunk, E);
    for (int e = e0 + tid; e < e1; e += 256)
        atomicAdd(&hist[dst[e] >> 7], 1);
    __syncthreads();
    for (int b = tid; b < nbins; b += 256) {
        int h = hist[b];
        ofs[b] = (h > 0) ? atomicAdd(&binCnt[b], h) : 0;
    }
    __syncthreads();
    for (int e = e0 + tid; e < e1; e += 256) {
        int d = dst[e];
        int b = d >> 7;
        int p = atomicAdd(&ofs[b], 1);
        if (p < BINCAP)
            binned[(size_t)b * BINCAP + p] = (unsigned)src[e] | ((unsigned)(d & 127) << 16);
    }
}

// ---------------- CSR build, phase 2: per-bin exact CSR via LDS, coalesced flush ----------------
__global__ __launch_bounds__(256) void bin_to_csr(const int* __restrict__ binCnt,
                                                  const unsigned* __restrict__ binned,
                                                  int* __restrict__ bucket,
                                                  int2* __restrict__ meta, int N)
{
    __shared__ int dcnt[128], ps[128], dpos[128];
    __shared__ int sbuf[BSTRIDE];
    __shared__ int tot_s;
    int b = blockIdx.x, tid = threadIdx.x;
    int nb = min(binCnt[b], BINCAP);
    size_t inbase = (size_t)b * BINCAP;
    size_t outbase = (size_t)b * BSTRIDE;
    if (tid < 128) dcnt[tid] = 0;
    __syncthreads();
    for (int i = tid; i < nb; i += 256)
        atomicAdd(&dcnt[(binned[inbase + i] >> 16) & 127], 1);
    __syncthreads();
    int pc = 0;
    if (tid < 128) { pc = (dcnt[tid] + 3) & ~3; ps[tid] = pc; }
    __syncthreads();
    for (int o = 1; o < 128; o <<= 1) {
        int v = (tid < 128 && tid >= o) ? ps[tid - o] : 0;
        __syncthreads();
        if (tid < 128) ps[tid] += v;
        __syncthreads();
    }
    if (tid < 128) {
        int dofs = ps[tid] - pc;
        dpos[tid] = dofs;
        for (int k = dcnt[tid]; k < pc; ++k) sbuf[dofs + k] = 0;   // zero pad slots
        int gd = b * 128 + tid;
        if (gd < N) meta[gd] = make_int2((int)outbase + dofs, dcnt[tid]);
        if (tid == 127) tot_s = ps[127];
    }
    __syncthreads();
    for (int i = tid; i < nb; i += 256) {
        unsigned u = binned[inbase + i];
        int p = atomicAdd(&dpos[(u >> 16) & 127], 1);
        sbuf[p] = (int)(u & 0xFFFFu);
    }
    __syncthreads();
    int tot = min(tot_s, BSTRIDE);
    for (int i = tid; i < tot; i += 256)
        bucket[outbase + i] = sbuf[i];
}

// ---------------- degree-balanced permutation: counting sort by degree ----------------
__global__ void deg_hist(const int2* __restrict__ meta, int* __restrict__ hist, int N) {
    __shared__ int lh[256];
    int tid = threadIdx.x;
    lh[tid] = 0;
    __syncthreads();
    int i = blockIdx.x * blockDim.x + tid;
    int stride = gridDim.x * blockDim.x;
    for (; i < N; i += stride)
        atomicAdd(&lh[min(meta[i].y, 255)], 1);
    __syncthreads();
    if (lh[tid] > 0) atomicAdd(&hist[tid], lh[tid]);
}

__global__ void scan_hist(const int* __restrict__ hist, int* __restrict__ dofs) {
    __shared__ int b[256];
    int t = threadIdx.x;
    int v = hist[t];
    b[t] = v;
    __syncthreads();
    for (int o = 1; o < 256; o <<= 1) {
        int x = (t >= o) ? b[t - o] : 0;
        __syncthreads();
        b[t] += x;
        __syncthreads();
    }
    dofs[t] = b[t] - v;   // exclusive
}

__global__ void perm_scatter(const int2* __restrict__ meta, int* __restrict__ dofs,
                             int* __restrict__ perm, int N) {
    int i = blockIdx.x * blockDim.x + threadIdx.x;
    int stride = gridDim.x * blockDim.x;
    for (; i < N; i += stride) {
        int pos = atomicAdd(&dofs[min(meta[i].y, 255)], 1);
        perm[pos] = i;
    }
}

// ---------------- Wt build: fp16 transposed weights Wt[c][k] = W[k][c] ----------------
__global__ void wt_build(const float* __restrict__ Wl0, const float* __restrict__ Wr0,
                         const float* __restrict__ Wl1, const float* __restrict__ Wr1,
                         const float* __restrict__ Wl2, const float* __restrict__ Wr2,
                         __half* __restrict__ Wt0, __half* __restrict__ Wt1,
                         __half* __restrict__ Wt2) {
    int i = blockIdx.x * blockDim.x + threadIdx.x;
    const int T01 = 256 * 128, T2 = 80 * 128;
    if (i < T01) {
        int c = i >> 7, k = i & 127;
        float v = (c < 128) ? Wl0[k * 128 + c] : Wr0[k * 128 + (c - 128)];
        Wt0[i] = __float2half(v);
    } else if (i < 2 * T01) {
        int j = i - T01;
        int c = j >> 7, k = j & 127;
        float v = (c < 128) ? Wl1[k * 128 + c] : Wr1[k * 128 + (c - 128)];
        Wt1[j] = __float2half(v);
    } else if (i < 2 * T01 + T2) {
        int j = i - 2 * T01;
        int c = j >> 7, k = j & 127;
        float v = (c < 40) ? Wl2[k * 40 + c] : Wr2[k * 40 + (c - 40)];
        Wt2[j] = __float2half(v);
    }
}

// ---------------- MFMA projection (input fp32 or fp16 via HIN) ----------------
template<int OUTH, bool HIN>
__global__ __launch_bounds__(256) void proj_mfma(const void* __restrict__ xin,
                                                 const __half* __restrict__ Wt,
                                                 __half* __restrict__ xl,
                                                 __half* __restrict__ xr,
                                                 int n)
{
    constexpr int OUTT = 2 * OUTH;
    constexpr int CT = OUTT / 16;
    __shared__ uint4 lds[1024 + OUTT * 16];
    int t = threadIdx.x;
    int r0 = blockIdx.x * 64;
    {
        int row = t >> 2;
        int k0 = (t & 3) * 32;
        int gr = r0 + row;
        #pragma unroll
        for (int s = 0; s < 4; ++s) {
            union { uint4 u; _Float16 h[8]; } pk;
            if (gr < n) {
                if constexpr (HIN) {
                    const uint4* xp = (const uint4*)((const __half*)xin + (size_t)gr * 128 + k0);
                    pk.u = xp[s];
                } else {
                    const float4* xp = (const float4*)((const float*)xin + (size_t)gr * 128 + k0 + s * 8);
                    float4 f0 = xp[0], f1 = xp[1];
                    pk.h[0] = (_Float16)f0.x; pk.h[1] = (_Float16)f0.y;
                    pk.h[2] = (_Float16)f0.z; pk.h[3] = (_Float16)f0.w;
                    pk.h[4] = (_Float16)f1.x; pk.h[5] = (_Float16)f1.y;
                    pk.h[6] = (_Float16)f1.z; pk.h[7] = (_Float16)f1.w;
                }
            } else {
                pk.u = make_uint4(0, 0, 0, 0);
            }
            int j = (t & 3) * 4 + s;
            lds[row * 16 + (j ^ (row & 7))] = pk.u;
        }
    }
    {
        const uint4* Wtv = (const uint4*)Wt;
        for (int m = t; m < OUTT * 16; m += 256) {
            int c = m >> 4, j = m & 15;
            lds[1024 + c * 16 + (j ^ (c & 7))] = Wtv[m];
        }
    }
    __syncthreads();
    int w = t >> 6, l = t & 63;
    int lr = l & 15, lg = l >> 4;
    half8 af[4];
    {
        int row = w * 16 + lr;
        #pragma unroll
        for (int kb = 0; kb < 4; ++kb) {
            int j = kb * 4 + lg;
            af[kb] = *reinterpret_cast<const half8*>(&lds[row * 16 + (j ^ (row & 7))]);
        }
    }
    f32x4 acc[CT];
    #pragma unroll
    for (int ct = 0; ct < CT; ++ct) acc[ct] = (f32x4){0.f, 0.f, 0.f, 0.f};
    int csw = lr & 7;
    #pragma unroll
    for (int ct = 0; ct < CT; ++ct) {
        int c = ct * 16 + lr;
        #pragma unroll
        for (int kb = 0; kb < 4; ++kb) {
            int j = kb * 4 + lg;
            half8 bf = *reinterpret_cast<const half8*>(&lds[1024 + c * 16 + (j ^ csw)]);
            acc[ct] = __builtin_amdgcn_mfma_f32_16x16x32_f16(af[kb], bf, acc[ct], 0, 0, 0);
        }
    }
    #pragma unroll
    for (int ct = 0; ct < CT; ++ct) {
        int c = ct * 16 + lr;
        #pragma unroll
        for (int i = 0; i < 4; ++i) {
            int gr = r0 + w * 16 + lg * 4 + i;
            if (gr < n) {
                __half h = __float2half(acc[ct][i]);
                if (c < OUTH) xl[(size_t)gr * OUTH + c] = h;
                else          xr[(size_t)gr * OUTH + (c - OUTH)] = h;
            }
        }
    }
}

// ---------------- fused per-node GATv2, HC=128: one node per 16-lane group ----------------
// degree-sorted perm; software-pipelined prefetch (next indices + 4 gathers issued
// before current compute); no-max softmax; fma_mix accumulation.
__global__ void aggr128(const int* __restrict__ perm,
                        const int2* __restrict__ meta, const int* __restrict__ bucket,
                        const __half* __restrict__ xlh, const __half* __restrict__ xrh,
                        const float* __restrict__ att, const float* __restrict__ bias,
                        __half* __restrict__ outp, int N, int do_relu)
{
    int wave = threadIdx.x >> 6;
    int lane = threadIdx.x & 63;
    int grp = lane >> 4;
    int j = lane & 15;
    int ndv = (blockIdx.x * (blockDim.x >> 6) + wave) * 4 + grp;
    if (ndv >= N) return;
    int nd = perm[ndv];
    union { uint4 u; h2 h[4]; } rq;
    rq.u = ((const uint4*)xrh)[(size_t)nd * 16 + j];
    h2 a2[4];
    {
        float4 t0 = ((const float4*)att)[2 * j];
        float4 t1 = ((const float4*)att)[2 * j + 1];
        a2[0] = h2{(_Float16)t0.x, (_Float16)t0.y};
        a2[1] = h2{(_Float16)t0.z, (_Float16)t0.w};
        a2[2] = h2{(_Float16)t1.x, (_Float16)t1.y};
        a2[3] = h2{(_Float16)t1.z, (_Float16)t1.w};
    }
    const uint4* xlv = (const uint4*)xlh;
    int2 md = meta[nd];
    int beg = md.x, deg = md.y;
    const int* brow = bucket + beg;
    const h2 c02 = h2{(_Float16)0.2f, (_Float16)0.2f};
    float s0 = 0.f, s1 = 0.f, s2 = 0.f, s3 = 0.f;
    float o0[8], o1[8], o2[8], o3[8];
    #pragma unroll
    for (int i = 0; i < 8; ++i) { o0[i] = 0.f; o1[i] = 0.f; o2[i] = 0.f; o3[i] = 0.f; }
    // prologue: indices + gathers for p=0 (deg >= 1 always: self-loop)
    uint4 qa0, qa1, qa2, qa3;
    {
        int4 ss = *(const int4*)(brow);
        qa0 = xlv[(size_t)ss.x * 16 + j];
        qa1 = xlv[(size_t)ss.y * 16 + j];
        qa2 = xlv[(size_t)ss.z * 16 + j];
        qa3 = xlv[(size_t)ss.w * 16 + j];
    }
    for (int p = 0; p < deg; p += 4) {
        // issue next iteration's indices + gathers before computing current
        uint4 qb0, qb1, qb2, qb3;
        {
            int pn = (p + 4 < deg) ? p + 4 : p;
            int4 sn = *(const int4*)(brow + pn);
            qb0 = xlv[(size_t)sn.x * 16 + j];
            qb1 = xlv[(size_t)sn.y * 16 + j];
            qb2 = xlv[(size_t)sn.z * 16 + j];
            qb3 = xlv[(size_t)sn.w * 16 + j];
        }
        union { uint4 u; h2 h[4]; } q;
        {
            q.u = qa0;
            float t = 0.f;
            #pragma unroll
            for (int i = 0; i < 4; ++i) {
                h2 v2 = q.h[i] + rq.h[i];
                h2 lk = __builtin_elementwise_max(v2, v2 * c02);
                t = hdot2(lk, a2[i], t);
            }
            t = dpp_add_xor1(t);
            float pe = __expf(t);               // slot 0 always valid (p < deg)
            s0 += pe;
            #pragma unroll
            for (int i = 0; i < 4; ++i) {
                o0[2*i]   = fmaf(pe, (float)q.h[i][0], o0[2*i]);
                o0[2*i+1] = fmaf(pe, (float)q.h[i][1], o0[2*i+1]);
            }
        }
        {
            q.u = qa1;
            float t = 0.f;
            #pragma unroll
            for (int i = 0; i < 4; ++i) {
                h2 v2 = q.h[i] + rq.h[i];
                h2 lk = __builtin_elementwise_max(v2, v2 * c02);
                t = hdot2(lk, a2[i], t);
            }
            t = dpp_add_xor1(t);
            float pe = (p + 1 < deg) ? __expf(t) : 0.f;
            s1 += pe;
            #pragma unroll
            for (int i = 0; i < 4; ++i) {
                o1[2*i]   = fmaf(pe, (float)q.h[i][0], o1[2*i]);
                o1[2*i+1] = fmaf(pe, (float)q.h[i][1], o1[2*i+1]);
            }
        }
        {
            q.u = qa2;
            float t = 0.f;
            #pragma unroll
            for (int i = 0; i < 4; ++i) {
                h2 v2 = q.h[i] + rq.h[i];
                h2 lk = __builtin_elementwise_max(v2, v2 * c02);
                t = hdot2(lk, a2[i], t);
            }
            t = dpp_add_xor1(t);
            float pe = (p + 2 < deg) ? __expf(t) : 0.f;
            s2 += pe;
            #pragma unroll
            for (int i = 0; i < 4; ++i) {
                o2[2*i]   = fmaf(pe, (float)q.h[i][0], o2[2*i]);
                o2[2*i+1] = fmaf(pe, (float)q.h[i][1], o2[2*i+1]);
            }
        }
        {
            q.u = qa3;
            float t = 0.f;
            #pragma unroll
            for (int i = 0; i < 4; ++i) {
                h2 v2 = q.h[i] + rq.h[i];
                h2 lk = __builtin_elementwise_max(v2, v2 * c02);
                t = hdot2(lk, a2[i], t);
            }
            t = dpp_add_xor1(t);
            float pe = (p + 3 < deg) ? __expf(t) : 0.f;
            s3 += pe;
            #pragma unroll
            for (int i = 0; i < 4; ++i) {
                o3[2*i]   = fmaf(pe, (float)q.h[i][0], o3[2*i]);
                o3[2*i+1] = fmaf(pe, (float)q.h[i][1], o3[2*i+1]);
            }
        }
        qa0 = qb0; qa1 = qb1; qa2 = qb2; qa3 = qb3;
    }
    float s = (s0 + s1) + (s2 + s3);
    {
        float inv = 1.f / fmaxf(s, 1e-16f);
        float4 b0 = ((const float4*)bias)[2 * j];
        float4 b1 = ((const float4*)bias)[2 * j + 1];
        float w[8];
        #pragma unroll
        for (int i = 0; i < 8; ++i)
            w[i] = ((o0[i] + o1[i]) + (o2[i] + o3[i])) * inv;
        w[0] += b0.x; w[1] += b0.y; w[2] += b0.z; w[3] += b0.w;
        w[4] += b1.x; w[5] += b1.y; w[6] += b1.z; w[7] += b1.w;
        if (do_relu) {
            #pragma unroll
            for (int i = 0; i < 8; ++i) w[i] = fmaxf(w[i], 0.f);
        }
        union { uint4 u; __half2 h[4]; } ow;
        ow.h[0] = __floats2half2_rn(w[0], w[1]);
        ow.h[1] = __floats2half2_rn(w[2], w[3]);
        ow.h[2] = __floats2half2_rn(w[4], w[5]);
        ow.h[3] = __floats2half2_rn(w[6], w[7]);
        ((uint4*)outp)[(size_t)nd * 16 + j] = ow.u;
    }
}

// ---------------- fused per-node pipeline, HC=40: one node per 16-lane group, fp32 out ----------------
__global__ void aggr40(const int* __restrict__ perm,
                       const int2* __restrict__ meta, const int* __restrict__ bucket,
                       const __half* __restrict__ xlh, const __half* __restrict__ xrh,
                       const float* __restrict__ att, const float* __restrict__ bias,
                       float* __restrict__ outp, int N)
{
    int wave = threadIdx.x >> 6;
    int lane = threadIdx.x & 63;
    int grp = lane >> 4;
    int j = lane & 15;
    int ndv = (blockIdx.x * (blockDim.x >> 6) + wave) * 4 + grp;
    if (ndv >= N) return;
    int nd = perm[ndv];
    bool act = (j < 10);
    union { uint2 u; h2 h[2]; } rq;
    rq.u = make_uint2(0, 0);
    h2 a2[2] = {h2{(_Float16)0.f, (_Float16)0.f}, h2{(_Float16)0.f, (_Float16)0.f}};
    if (act) {
        rq.u = *(const uint2*)(xrh + (size_t)nd * 40 + 4 * j);
        float4 a4 = ((const float4*)att)[j];
        a2[0] = h2{(_Float16)a4.x, (_Float16)a4.y};
        a2[1] = h2{(_Float16)a4.z, (_Float16)a4.w};
    }
    int2 md = meta[nd];
    int beg = md.x, deg = md.y;
    const int* brow = bucket + beg;
    const h2 c02 = h2{(_Float16)0.2f, (_Float16)0.2f};
    float s0 = 0.f, s1 = 0.f;
    float o0[4], o1[4];
    #pragma unroll
    for (int i = 0; i < 4; ++i) { o0[i] = 0.f; o1[i] = 0.f; }
    uint2 qa0, qa1, qa2, qa3;
    {
        int4 ss = *(const int4*)(brow);
        qa0 = act ? *(const uint2*)(xlh + (size_t)ss.x * 40 + 4 * j) : make_uint2(0, 0);
        qa1 = act ? *(const uint2*)(xlh + (size_t)ss.y * 40 + 4 * j) : make_uint2(0, 0);
        qa2 = act ? *(const uint2*)(xlh + (size_t)ss.z * 40 + 4 * j) : make_uint2(0, 0);
        qa3 = act ? *(const uint2*)(xlh + (size_t)ss.w * 40 + 4 * j) : make_uint2(0, 0);
    }
    for (int p = 0; p < deg; p += 4) {
        uint2 qb0, qb1, qb2, qb3;
        {
            int pn = (p + 4 < deg) ? p + 4 : p;
            int4 sn = *(const int4*)(brow + pn);
            qb0 = act ? *(const uint2*)(xlh + (size_t)sn.x * 40 + 4 * j) : make_uint2(0, 0);
            qb1 = act ? *(const uint2*)(xlh + (size_t)sn.y * 40 + 4 * j) : make_uint2(0, 0);
            qb2 = act ? *(const uint2*)(xlh + (size_t)sn.z * 40 + 4 * j) : make_uint2(0, 0);
            qb3 = act ? *(const uint2*)(xlh + (size_t)sn.w * 40 + 4 * j) : make_uint2(0, 0);
        }
        union { uint2 u; h2 h[2]; } q;
        {
            q.u = qa0;
            float t = 0.f;
            #pragma unroll
            for (int i = 0; i < 2; ++i) {
                h2 v2 = q.h[i] + rq.h[i];
                h2 lk = __builtin_elementwise_max(v2, v2 * c02);
                t = hdot2(lk, a2[i], t);
            }
            t = dpp_add_xor1(t); t = dpp_add_xor2(t);
            t += __shfl_xor(t, 4); t += __shfl_xor(t, 8);
            float pe = __expf(t);
            s0 += pe;
            #pragma unroll
            for (int i = 0; i < 2; ++i) {
                o0[2*i]   = fmaf(pe, (float)q.h[i][0], o0[2*i]);
                o0[2*i+1] = fmaf(pe, (float)q.h[i][1], o0[2*i+1]);
            }
        }
        {
            q.u = qa1;
            float t = 0.f;
            #pragma unroll
            for (int i = 0; i < 2; ++i) {
                h2 v2 = q.h[i] + rq.h[i];
                h2 lk = __builtin_elementwise_max(v2, v2 * c02);
                t = hdot2(lk, a2[i], t);
            }
            t = dpp_add_xor1(t); t = dpp_add_xor2(t);
            t += __shfl_xor(t, 4); t += __shfl_xor(t, 8);
            float pe = (p + 1 < deg) ? __expf(t) : 0.f;
            s1 += pe;
            #pragma unroll
            for (int i = 0; i < 2; ++i) {
                o1[2*i]   = fmaf(pe, (float)q.h[i][0], o1[2*i]);
                o1[2*i+1] = fmaf(pe, (float)q.h[i][1], o1[2*i+1]);
            }
        }
        {
            q.u = qa2;
            float t = 0.f;
            #pragma unroll
            for (int i = 0; i < 2; ++i) {
                h2 v2 = q.h[i] + rq.h[i];
                h2 lk = __builtin_elementwise_max(v2, v2 * c02);
                t = hdot2(lk, a2[i], t);
            }
            t = dpp_add_xor1(t); t = dpp_add_xor2(t);
            t += __shfl_xor(t, 4); t += __shfl_xor(t, 8);
            float pe = (p + 2 < deg) ? __expf(t) : 0.f;
            s0 += pe;
            #pragma unroll
            for (int i = 0; i < 2; ++i) {
                o0[2*i]   = fmaf(pe, (float)q.h[i][0], o0[2*i]);
                o0[2*i+1] = fmaf(pe, (float)q.h[i][1], o0[2*i+1]);
            }
        }
        {
            q.u = qa3;
            float t = 0.f;
            #pragma unroll
            for (int i = 0; i < 2; ++i) {
                h2 v2 = q.h[i] + rq.h[i];
                h2 lk = __builtin_elementwise_max(v2, v2 * c02);
                t = hdot2(lk, a2[i], t);
            }
            t = dpp_add_xor1(t); t = dpp_add_xor2(t);
            t += __shfl_xor(t, 4); t += __shfl_xor(t, 8);
            float pe = (p + 3 < deg) ? __expf(t) : 0.f;
            s1 += pe;
            #pragma unroll
            for (int i = 0; i < 2; ++i) {
                o1[2*i]   = fmaf(pe, (float)q.h[i][0], o1[2*i]);
                o1[2*i+1] = fmaf(pe, (float)q.h[i][1], o1[2*i+1]);
            }
        }
        qa0 = qb0; qa1 = qb1; qa2 = qb2; qa3 = qb3;
    }
    if (act) {
        float s = s0 + s1;
        float inv = 1.f / fmaxf(s, 1e-16f);
        float4 b4 = ((const float4*)bias)[j];
        float4 w;
        w.x = (o0[0] + o1[0]) * inv + b4.x;
        w.y = (o0[1] + o1[1]) * inv + b4.y;
        w.z = (o0[2] + o1[2]) * inv + b4.z;
        w.w = (o0[3] + o1[3]) * inv + b4.w;
        *(float4*)(outp + (size_t)nd * 40 + 4 * j) = w;
    }
}

extern "C" void kernel_launch(void* const* d_in, const int* in_sizes, int n_in,
                              void* d_out, int out_size, void* d_ws, size_t ws_size,
                              hipStream_t stream)
{
    const float* x    = (const float*)d_in[0];
    const int*   esrc = (const int*)d_in[1];
    const int*   edst = (const int*)d_in[2];
    const float* Wl0  = (const float*)d_in[3];
    const float* Wr0  = (const float*)d_in[4];
    const float* att0 = (const float*)d_in[5];
    const float* b0   = (const float*)d_in[6];
    const float* Wl1  = (const float*)d_in[7];
    const float* Wr1  = (const float*)d_in[8];
    const float* att1 = (const float*)d_in[9];
    const float* b1   = (const float*)d_in[10];
    const float* Wl2  = (const float*)d_in[11];
    const float* Wr2  = (const float*)d_in[12];
    const float* att2 = (const float*)d_in[13];
    const float* b2   = (const float*)d_in[14];
    float* out = (float*)d_out;

    const int N = in_sizes[0] / 128;   // 50000 (pack requires N <= 65536)
    const int E = in_sizes[1];         // 850000
    const int nbins = (N + 127) / 128; // 391

    char* ws = (char*)d_ws;
    size_t off = 0;
    auto walloc = [&](size_t bytes) -> void* {
        void* p = ws + off;
        off = (off + bytes + 255) & ~(size_t)255;
        return p;
    };
    __half*   xlh    = (__half*)walloc((size_t)N * 128 * 2);
    __half*   xrh    = (__half*)walloc((size_t)N * 128 * 2);
    __half*   hbuf   = (__half*)walloc((size_t)N * 128 * 2);
    __half*   Wt0    = (__half*)walloc(256 * 128 * 2);
    __half*   Wt1    = (__half*)walloc(256 * 128 * 2);
    __half*   Wt2    = (__half*)walloc(80 * 128 * 2);
    int*      binCnt = (int*)walloc((size_t)nbins * 4);
    unsigned* binned = (unsigned*)walloc((size_t)nbins * BINCAP * 4);
    int*      bucket = (int*)walloc((size_t)nbins * BSTRIDE * 4);
    int2*     meta   = (int2*)walloc((size_t)N * 8);
    int*      hist   = (int*)walloc(256 * 4);
    int*      dofs   = (int*)walloc(256 * 4);
    int*      perm   = (int*)walloc((size_t)N * 4);

    // ---- fp16 transposed weights ----
    wt_build<<<(2 * 256 * 128 + 80 * 128 + 255) / 256, 256, 0, stream>>>(
        Wl0, Wr0, Wl1, Wr1, Wl2, Wr2, Wt0, Wt1, Wt2);

    // ---- CSR build: bin then per-bin LDS CSR ----
    hipMemsetAsync(binCnt, 0, (size_t)nbins * 4, stream);
    hipMemsetAsync(hist, 0, 256 * 4, stream);
    bin_edges<<<256, 256, 0, stream>>>(esrc, edst, binCnt, binned, E, nbins);
    bin_to_csr<<<nbins, 256, 0, stream>>>(binCnt, binned, bucket, meta, N);

    // ---- degree-balanced node permutation (counting sort by degree) ----
    deg_hist<<<256, 256, 0, stream>>>(meta, hist, N);
    scan_hist<<<1, 256, 0, stream>>>(hist, dofs);
    perm_scatter<<<256, 256, 0, stream>>>(meta, dofs, perm, N);

    int nblk = (N + 15) / 16;  // aggr: 16 nodes per 256-thread block (4/wave)
    int pblk = (N + 63) / 64;  // proj: 64 rows per block

    // ---- layer 0 ----
    proj_mfma<128, false><<<pblk, 256, 0, stream>>>(x, Wt0, xlh, xrh, N);
    aggr128<<<nblk, 256, 0, stream>>>(perm, meta, bucket, xlh, xrh, att0, b0, hbuf, N, 1);
    // ---- layer 1 ----
    proj_mfma<128, true><<<pblk, 256, 0, stream>>>(hbuf, Wt1, xlh, xrh, N);
    aggr128<<<nblk, 256, 0, stream>>>(perm, meta, bucket, xlh, xrh, att1, b1, hbuf, N, 1);
    // ---- layer 2 ----
    proj_mfma<40, true><<<pblk, 256, 0, stream>>>(hbuf, Wt2, xlh, xrh, N);
    aggr40<<<nblk, 256, 0, stream>>>(perm, meta, bucket, xlh, xrh, att2, b2, out, N);
}

// Round 13
// 195.607 us; speedup vs baseline: 1.6936x; 1.6936x over previous
//
#include <hip/hip_runtime.h>
#include <hip/hip_fp16.h>
#include <cmath>

typedef _Float16 half8 __attribute__((ext_vector_type(8)));
typedef _Float16 h2 __attribute__((ext_vector_type(2)));
typedef float f32x4 __attribute__((ext_vector_type(4)));

#define BINCAP 2600              // mean edges/bin ~2176, +9 sigma guard
#define BSTRIDE (BINCAP + 384)   // room for per-dst pad-to-4 (128 dst x 3)
#define NBINS_MAX 512            // N<=65536 (16-bit src pack also requires this)
#define PBLK 64                  // blocks for perm build (atomic fan-in per bin = 64)

// DPP cross-lane adds within quads (VALU pipe, no LDS): t += t[lane^mask]
__device__ __forceinline__ float dpp_add_xor1(float t) {
    int r = __builtin_amdgcn_update_dpp(0, __float_as_int(t), 0xB1, 0xF, 0xF, true);
    return t + __int_as_float(r);
}
__device__ __forceinline__ float dpp_add_xor2(float t) {
    int r = __builtin_amdgcn_update_dpp(0, __float_as_int(t), 0x4E, 0xF, 0xF, true);
    return t + __int_as_float(r);
}

__device__ __forceinline__ float hdot2(h2 a, h2 b, float acc) {
#if __has_builtin(__builtin_amdgcn_fdot2)
    return __builtin_amdgcn_fdot2(a, b, acc, false);
#else
    return acc + (float)a[0] * (float)b[0] + (float)a[1] * (float)b[1];
#endif
}

// ---------------- CSR build, phase 1: bin by dst>>7 (block-exclusive segments) ----------------
__global__ __launch_bounds__(256) void bin_edges(const int* __restrict__ src,
                                                 const int* __restrict__ dst,
                                                 int* __restrict__ binCnt,
                                                 unsigned* __restrict__ binned,
                                                 int E, int nbins)
{
    __shared__ int hist[NBINS_MAX];
    __shared__ int ofs[NBINS_MAX];
    int tid = threadIdx.x;
    for (int i = tid; i < nbins; i += 256) hist[i] = 0;
    __syncthreads();
    int chunk = (E + gridDim.x - 1) / gridDim.x;
    int e0 = blockIdx.x * chunk;
    int e1 = min(e0 + chunk, E);
    for (int e = e0 + tid; e < e1; e += 256)
        atomicAdd(&hist[dst[e] >> 7], 1);
    __syncthreads();
    for (int b = tid; b < nbins; b += 256) {
        int h = hist[b];
        ofs[b] = (h > 0) ? atomicAdd(&binCnt[b], h) : 0;
    }
    __syncthreads();
    for (int e = e0 + tid; e < e1; e += 256) {
        int d = dst[e];
        int b = d >> 7;
        int p = atomicAdd(&ofs[b], 1);
        if (p < BINCAP)
            binned[(size_t)b * BINCAP + p] = (unsigned)src[e] | ((unsigned)(d & 127) << 16);
    }
}

// ---------------- CSR build, phase 2: per-bin exact CSR via LDS, coalesced flush ----------------
__global__ __launch_bounds__(256) void bin_to_csr(const int* __restrict__ binCnt,
                                                  const unsigned* __restrict__ binned,
                                                  int* __restrict__ bucket,
                                                  int2* __restrict__ meta, int N)
{
    __shared__ int dcnt[128], ps[128], dpos[128];
    __shared__ int sbuf[BSTRIDE];
    __shared__ int tot_s;
    int b = blockIdx.x, tid = threadIdx.x;
    int nb = min(binCnt[b], BINCAP);
    size_t inbase = (size_t)b * BINCAP;
    size_t outbase = (size_t)b * BSTRIDE;
    if (tid < 128) dcnt[tid] = 0;
    __syncthreads();
    for (int i = tid; i < nb; i += 256)
        atomicAdd(&dcnt[(binned[inbase + i] >> 16) & 127], 1);
    __syncthreads();
    int pc = 0;
    if (tid < 128) { pc = (dcnt[tid] + 3) & ~3; ps[tid] = pc; }
    __syncthreads();
    for (int o = 1; o < 128; o <<= 1) {
        int v = (tid < 128 && tid >= o) ? ps[tid - o] : 0;
        __syncthreads();
        if (tid < 128) ps[tid] += v;
        __syncthreads();
    }
    if (tid < 128) {
        int dofs = ps[tid] - pc;
        dpos[tid] = dofs;
        for (int k = dcnt[tid]; k < pc; ++k) sbuf[dofs + k] = 0;   // zero pad slots
        int gd = b * 128 + tid;
        if (gd < N) meta[gd] = make_int2((int)outbase + dofs, dcnt[tid]);
        if (tid == 127) tot_s = ps[127];
    }
    __syncthreads();
    for (int i = tid; i < nb; i += 256) {
        unsigned u = binned[inbase + i];
        int p = atomicAdd(&dpos[(u >> 16) & 127], 1);
        sbuf[p] = (int)(u & 0xFFFFu);
    }
    __syncthreads();
    int tot = min(tot_s, BSTRIDE);
    for (int i = tid; i < tot; i += 256)
        bucket[outbase + i] = sbuf[i];
}

// ---------------- degree-balanced permutation: low-contention counting sort ----------------
__global__ __launch_bounds__(256) void deg_hist(const int2* __restrict__ meta,
                                                int* __restrict__ hist, int N) {
    __shared__ int lh[256];
    int tid = threadIdx.x;
    lh[tid] = 0;
    __syncthreads();
    int chunk = (N + gridDim.x - 1) / gridDim.x;
    int i0 = blockIdx.x * chunk;
    int i1 = min(i0 + chunk, N);
    for (int i = i0 + tid; i < i1; i += 256)
        atomicAdd(&lh[min(meta[i].y, 255)], 1);
    __syncthreads();
    if (lh[tid] > 0) atomicAdd(&hist[tid], lh[tid]);
}

__global__ void scan_hist(const int* __restrict__ hist, int* __restrict__ dofs) {
    __shared__ int b[256];
    int t = threadIdx.x;
    int v = hist[t];
    b[t] = v;
    __syncthreads();
    for (int o = 1; o < 256; o <<= 1) {
        int x = (t >= o) ? b[t - o] : 0;
        __syncthreads();
        b[t] += x;
        __syncthreads();
    }
    dofs[t] = b[t] - v;   // exclusive
}

// per-block: LDS hist -> one global reservation per active bin -> local scatter
__global__ __launch_bounds__(256) void perm_build(const int2* __restrict__ meta,
                                                  int* __restrict__ dofs,
                                                  int* __restrict__ perm, int N) {
    __shared__ int lh[256];
    __shared__ int lbase[256];
    int tid = threadIdx.x;
    lh[tid] = 0;
    __syncthreads();
    int chunk = (N + gridDim.x - 1) / gridDim.x;
    int i0 = blockIdx.x * chunk;
    int i1 = min(i0 + chunk, N);
    for (int i = i0 + tid; i < i1; i += 256)
        atomicAdd(&lh[min(meta[i].y, 255)], 1);
    __syncthreads();
    int h = lh[tid];
    lbase[tid] = (h > 0) ? atomicAdd(&dofs[tid], h) : 0;
    __syncthreads();
    lh[tid] = 0;   // reuse as local cursor
    __syncthreads();
    for (int i = i0 + tid; i < i1; i += 256) {
        int b = min(meta[i].y, 255);
        int p = lbase[b] + atomicAdd(&lh[b], 1);
        perm[p] = i;
    }
}

// ---------------- Wt build: fp16 transposed weights Wt[c][k] = W[k][c] ----------------
__global__ void wt_build(const float* __restrict__ Wl0, const float* __restrict__ Wr0,
                         const float* __restrict__ Wl1, const float* __restrict__ Wr1,
                         const float* __restrict__ Wl2, const float* __restrict__ Wr2,
                         __half* __restrict__ Wt0, __half* __restrict__ Wt1,
                         __half* __restrict__ Wt2) {
    int i = blockIdx.x * blockDim.x + threadIdx.x;
    const int T01 = 256 * 128, T2 = 80 * 128;
    if (i < T01) {
        int c = i >> 7, k = i & 127;
        float v = (c < 128) ? Wl0[k * 128 + c] : Wr0[k * 128 + (c - 128)];
        Wt0[i] = __float2half(v);
    } else if (i < 2 * T01) {
        int j = i - T01;
        int c = j >> 7, k = j & 127;
        float v = (c < 128) ? Wl1[k * 128 + c] : Wr1[k * 128 + (c - 128)];
        Wt1[j] = __float2half(v);
    } else if (i < 2 * T01 + T2) {
        int j = i - 2 * T01;
        int c = j >> 7, k = j & 127;
        float v = (c < 40) ? Wl2[k * 40 + c] : Wr2[k * 40 + (c - 40)];
        Wt2[j] = __float2half(v);
    }
}

// ---------------- MFMA projection (input fp32 or fp16 via HIN) ----------------
template<int OUTH, bool HIN>
__global__ __launch_bounds__(256) void proj_mfma(const void* __restrict__ xin,
                                                 const __half* __restrict__ Wt,
                                                 __half* __restrict__ xl,
                                                 __half* __restrict__ xr,
                                                 int n)
{
    constexpr int OUTT = 2 * OUTH;
    constexpr int CT = OUTT / 16;
    __shared__ uint4 lds[1024 + OUTT * 16];
    int t = threadIdx.x;
    int r0 = blockIdx.x * 64;
    {
        int row = t >> 2;
        int k0 = (t & 3) * 32;
        int gr = r0 + row;
        #pragma unroll
        for (int s = 0; s < 4; ++s) {
            union { uint4 u; _Float16 h[8]; } pk;
            if (gr < n) {
                if constexpr (HIN) {
                    const uint4* xp = (const uint4*)((const __half*)xin + (size_t)gr * 128 + k0);
                    pk.u = xp[s];
                } else {
                    const float4* xp = (const float4*)((const float*)xin + (size_t)gr * 128 + k0 + s * 8);
                    float4 f0 = xp[0], f1 = xp[1];
                    pk.h[0] = (_Float16)f0.x; pk.h[1] = (_Float16)f0.y;
                    pk.h[2] = (_Float16)f0.z; pk.h[3] = (_Float16)f0.w;
                    pk.h[4] = (_Float16)f1.x; pk.h[5] = (_Float16)f1.y;
                    pk.h[6] = (_Float16)f1.z; pk.h[7] = (_Float16)f1.w;
                }
            } else {
                pk.u = make_uint4(0, 0, 0, 0);
            }
            int j = (t & 3) * 4 + s;
            lds[row * 16 + (j ^ (row & 7))] = pk.u;
        }
    }
    {
        const uint4* Wtv = (const uint4*)Wt;
        for (int m = t; m < OUTT * 16; m += 256) {
            int c = m >> 4, j = m & 15;
            lds[1024 + c * 16 + (j ^ (c & 7))] = Wtv[m];
        }
    }
    __syncthreads();
    int w = t >> 6, l = t & 63;
    int lr = l & 15, lg = l >> 4;
    half8 af[4];
    {
        int row = w * 16 + lr;
        #pragma unroll
        for (int kb = 0; kb < 4; ++kb) {
            int j = kb * 4 + lg;
            af[kb] = *reinterpret_cast<const half8*>(&lds[row * 16 + (j ^ (row & 7))]);
        }
    }
    f32x4 acc[CT];
    #pragma unroll
    for (int ct = 0; ct < CT; ++ct) acc[ct] = (f32x4){0.f, 0.f, 0.f, 0.f};
    int csw = lr & 7;
    #pragma unroll
    for (int ct = 0; ct < CT; ++ct) {
        int c = ct * 16 + lr;
        #pragma unroll
        for (int kb = 0; kb < 4; ++kb) {
            int j = kb * 4 + lg;
            half8 bf = *reinterpret_cast<const half8*>(&lds[1024 + c * 16 + (j ^ csw)]);
            acc[ct] = __builtin_amdgcn_mfma_f32_16x16x32_f16(af[kb], bf, acc[ct], 0, 0, 0);
        }
    }
    #pragma unroll
    for (int ct = 0; ct < CT; ++ct) {
        int c = ct * 16 + lr;
        #pragma unroll
        for (int i = 0; i < 4; ++i) {
            int gr = r0 + w * 16 + lg * 4 + i;
            if (gr < n) {
                __half h = __float2half(acc[ct][i]);
                if (c < OUTH) xl[(size_t)gr * OUTH + c] = h;
                else          xr[(size_t)gr * OUTH + (c - OUTH)] = h;
            }
        }
    }
}

// ---------------- fused per-node GATv2, HC=128: one node per 16-lane group ----------------
__global__ void aggr128(const int* __restrict__ perm,
                        const int2* __restrict__ meta, const int* __restrict__ bucket,
                        const __half* __restrict__ xlh, const __half* __restrict__ xrh,
                        const float* __restrict__ att, const float* __restrict__ bias,
                        __half* __restrict__ outp, int N, int do_relu)
{
    int wave = threadIdx.x >> 6;
    int lane = threadIdx.x & 63;
    int grp = lane >> 4;
    int j = lane & 15;
    int ndv = (blockIdx.x * (blockDim.x >> 6) + wave) * 4 + grp;
    if (ndv >= N) return;
    int nd = perm[ndv];
    union { uint4 u; h2 h[4]; } rq;
    rq.u = ((const uint4*)xrh)[(size_t)nd * 16 + j];
    h2 a2[4];
    {
        float4 t0 = ((const float4*)att)[2 * j];
        float4 t1 = ((const float4*)att)[2 * j + 1];
        a2[0] = h2{(_Float16)t0.x, (_Float16)t0.y};
        a2[1] = h2{(_Float16)t0.z, (_Float16)t0.w};
        a2[2] = h2{(_Float16)t1.x, (_Float16)t1.y};
        a2[3] = h2{(_Float16)t1.z, (_Float16)t1.w};
    }
    const uint4* xlv = (const uint4*)xlh;
    int2 md = meta[nd];
    int beg = md.x, deg = md.y;
    const int* brow = bucket + beg;
    const h2 c02 = h2{(_Float16)0.2f, (_Float16)0.2f};
    float s0 = 0.f, s1 = 0.f, s2 = 0.f, s3 = 0.f;
    float o0[8], o1[8], o2[8], o3[8];
    #pragma unroll
    for (int i = 0; i < 8; ++i) { o0[i] = 0.f; o1[i] = 0.f; o2[i] = 0.f; o3[i] = 0.f; }
    uint4 qa0, qa1, qa2, qa3;
    {
        int4 ss = *(const int4*)(brow);
        qa0 = xlv[(size_t)ss.x * 16 + j];
        qa1 = xlv[(size_t)ss.y * 16 + j];
        qa2 = xlv[(size_t)ss.z * 16 + j];
        qa3 = xlv[(size_t)ss.w * 16 + j];
    }
    for (int p = 0; p < deg; p += 4) {
        uint4 qb0, qb1, qb2, qb3;
        {
            int pn = (p + 4 < deg) ? p + 4 : p;
            int4 sn = *(const int4*)(brow + pn);
            qb0 = xlv[(size_t)sn.x * 16 + j];
            qb1 = xlv[(size_t)sn.y * 16 + j];
            qb2 = xlv[(size_t)sn.z * 16 + j];
            qb3 = xlv[(size_t)sn.w * 16 + j];
        }
        union { uint4 u; h2 h[4]; } q;
        {
            q.u = qa0;
            float t = 0.f;
            #pragma unroll
            for (int i = 0; i < 4; ++i) {
                h2 v2 = q.h[i] + rq.h[i];
                h2 lk = __builtin_elementwise_max(v2, v2 * c02);
                t = hdot2(lk, a2[i], t);
            }
            t = dpp_add_xor1(t);
            float pe = __expf(t);
            s0 += pe;
            #pragma unroll
            for (int i = 0; i < 4; ++i) {
                o0[2*i]   = fmaf(pe, (float)q.h[i][0], o0[2*i]);
                o0[2*i+1] = fmaf(pe, (float)q.h[i][1], o0[2*i+1]);
            }
        }
        {
            q.u = qa1;
            float t = 0.f;
            #pragma unroll
            for (int i = 0; i < 4; ++i) {
                h2 v2 = q.h[i] + rq.h[i];
                h2 lk = __builtin_elementwise_max(v2, v2 * c02);
                t = hdot2(lk, a2[i], t);
            }
            t = dpp_add_xor1(t);
            float pe = (p + 1 < deg) ? __expf(t) : 0.f;
            s1 += pe;
            #pragma unroll
            for (int i = 0; i < 4; ++i) {
                o1[2*i]   = fmaf(pe, (float)q.h[i][0], o1[2*i]);
                o1[2*i+1] = fmaf(pe, (float)q.h[i][1], o1[2*i+1]);
            }
        }
        {
            q.u = qa2;
            float t = 0.f;
            #pragma unroll
            for (int i = 0; i < 4; ++i) {
                h2 v2 = q.h[i] + rq.h[i];
                h2 lk = __builtin_elementwise_max(v2, v2 * c02);
                t = hdot2(lk, a2[i], t);
            }
            t = dpp_add_xor1(t);
            float pe = (p + 2 < deg) ? __expf(t) : 0.f;
            s2 += pe;
            #pragma unroll
            for (int i = 0; i < 4; ++i) {
                o2[2*i]   = fmaf(pe, (float)q.h[i][0], o2[2*i]);
                o2[2*i+1] = fmaf(pe, (float)q.h[i][1], o2[2*i+1]);
            }
        }
        {
            q.u = qa3;
            float t = 0.f;
            #pragma unroll
            for (int i = 0; i < 4; ++i) {
                h2 v2 = q.h[i] + rq.h[i];
                h2 lk = __builtin_elementwise_max(v2, v2 * c02);
                t = hdot2(lk, a2[i], t);
            }
            t = dpp_add_xor1(t);
            float pe = (p + 3 < deg) ? __expf(t) : 0.f;
            s3 += pe;
            #pragma unroll
            for (int i = 0; i < 4; ++i) {
                o3[2*i]   = fmaf(pe, (float)q.h[i][0], o3[2*i]);
                o3[2*i+1] = fmaf(pe, (float)q.h[i][1], o3[2*i+1]);
            }
        }
        qa0 = qb0; qa1 = qb1; qa2 = qb2; qa3 = qb3;
    }
    float s = (s0 + s1) + (s2 + s3);
    {
        float inv = 1.f / fmaxf(s, 1e-16f);
        float4 b0 = ((const float4*)bias)[2 * j];
        float4 b1 = ((const float4*)bias)[2 * j + 1];
        float w[8];
        #pragma unroll
        for (int i = 0; i < 8; ++i)
            w[i] = ((o0[i] + o1[i]) + (o2[i] + o3[i])) * inv;
        w[0] += b0.x; w[1] += b0.y; w[2] += b0.z; w[3] += b0.w;
        w[4] += b1.x; w[5] += b1.y; w[6] += b1.z; w[7] += b1.w;
        if (do_relu) {
            #pragma unroll
            for (int i = 0; i < 8; ++i) w[i] = fmaxf(w[i], 0.f);
        }
        union { uint4 u; __half2 h[4]; } ow;
        ow.h[0] = __floats2half2_rn(w[0], w[1]);
        ow.h[1] = __floats2half2_rn(w[2], w[3]);
        ow.h[2] = __floats2half2_rn(w[4], w[5]);
        ow.h[3] = __floats2half2_rn(w[6], w[7]);
        ((uint4*)outp)[(size_t)nd * 16 + j] = ow.u;
    }
}

// ---------------- fused per-node pipeline, HC=40: one node per 16-lane group, fp32 out ----------------
__global__ void aggr40(const int* __restrict__ perm,
                       const int2* __restrict__ meta, const int* __restrict__ bucket,
                       const __half* __restrict__ xlh, const __half* __restrict__ xrh,
                       const float* __restrict__ att, const float* __restrict__ bias,
                       float* __restrict__ outp, int N)
{
    int wave = threadIdx.x >> 6;
    int lane = threadIdx.x & 63;
    int grp = lane >> 4;
    int j = lane & 15;
    int ndv = (blockIdx.x * (blockDim.x >> 6) + wave) * 4 + grp;
    if (ndv >= N) return;
    int nd = perm[ndv];
    bool act = (j < 10);
    union { uint2 u; h2 h[2]; } rq;
    rq.u = make_uint2(0, 0);
    h2 a2[2] = {h2{(_Float16)0.f, (_Float16)0.f}, h2{(_Float16)0.f, (_Float16)0.f}};
    if (act) {
        rq.u = *(const uint2*)(xrh + (size_t)nd * 40 + 4 * j);
        float4 a4 = ((const float4*)att)[j];
        a2[0] = h2{(_Float16)a4.x, (_Float16)a4.y};
        a2[1] = h2{(_Float16)a4.z, (_Float16)a4.w};
    }
    int2 md = meta[nd];
    int beg = md.x, deg = md.y;
    const int* brow = bucket + beg;
    const h2 c02 = h2{(_Float16)0.2f, (_Float16)0.2f};
    float s0 = 0.f, s1 = 0.f;
    float o0[4], o1[4];
    #pragma unroll
    for (int i = 0; i < 4; ++i) { o0[i] = 0.f; o1[i] = 0.f; }
    uint2 qa0, qa1, qa2, qa3;
    {
        int4 ss = *(const int4*)(brow);
        qa0 = act ? *(const uint2*)(xlh + (size_t)ss.x * 40 + 4 * j) : make_uint2(0, 0);
        qa1 = act ? *(const uint2*)(xlh + (size_t)ss.y * 40 + 4 * j) : make_uint2(0, 0);
        qa2 = act ? *(const uint2*)(xlh + (size_t)ss.z * 40 + 4 * j) : make_uint2(0, 0);
        qa3 = act ? *(const uint2*)(xlh + (size_t)ss.w * 40 + 4 * j) : make_uint2(0, 0);
    }
    for (int p = 0; p < deg; p += 4) {
        uint2 qb0, qb1, qb2, qb3;
        {
            int pn = (p + 4 < deg) ? p + 4 : p;
            int4 sn = *(const int4*)(brow + pn);
            qb0 = act ? *(const uint2*)(xlh + (size_t)sn.x * 40 + 4 * j) : make_uint2(0, 0);
            qb1 = act ? *(const uint2*)(xlh + (size_t)sn.y * 40 + 4 * j) : make_uint2(0, 0);
            qb2 = act ? *(const uint2*)(xlh + (size_t)sn.z * 40 + 4 * j) : make_uint2(0, 0);
            qb3 = act ? *(const uint2*)(xlh + (size_t)sn.w * 40 + 4 * j) : make_uint2(0, 0);
        }
        union { uint2 u; h2 h[2]; } q;
        {
            q.u = qa0;
            float t = 0.f;
            #pragma unroll
            for (int i = 0; i < 2; ++i) {
                h2 v2 = q.h[i] + rq.h[i];
                h2 lk = __builtin_elementwise_max(v2, v2 * c02);
                t = hdot2(lk, a2[i], t);
            }
            t = dpp_add_xor1(t); t = dpp_add_xor2(t);
            t += __shfl_xor(t, 4); t += __shfl_xor(t, 8);
            float pe = __expf(t);
            s0 += pe;
            #pragma unroll
            for (int i = 0; i < 2; ++i) {
                o0[2*i]   = fmaf(pe, (float)q.h[i][0], o0[2*i]);
                o0[2*i+1] = fmaf(pe, (float)q.h[i][1], o0[2*i+1]);
            }
        }
        {
            q.u = qa1;
            float t = 0.f;
            #pragma unroll
            for (int i = 0; i < 2; ++i) {
                h2 v2 = q.h[i] + rq.h[i];
                h2 lk = __builtin_elementwise_max(v2, v2 * c02);
                t = hdot2(lk, a2[i], t);
            }
            t = dpp_add_xor1(t); t = dpp_add_xor2(t);
            t += __shfl_xor(t, 4); t += __shfl_xor(t, 8);
            float pe = (p + 1 < deg) ? __expf(t) : 0.f;
            s1 += pe;
            #pragma unroll
            for (int i = 0; i < 2; ++i) {
                o1[2*i]   = fmaf(pe, (float)q.h[i][0], o1[2*i]);
                o1[2*i+1] = fmaf(pe, (float)q.h[i][1], o1[2*i+1]);
            }
        }
        {
            q.u = qa2;
            float t = 0.f;
            #pragma unroll
            for (int i = 0; i < 2; ++i) {
                h2 v2 = q.h[i] + rq.h[i];
                h2 lk = __builtin_elementwise_max(v2, v2 * c02);
                t = hdot2(lk, a2[i], t);
            }
            t = dpp_add_xor1(t); t = dpp_add_xor2(t);
            t += __shfl_xor(t, 4); t += __shfl_xor(t, 8);
            float pe = (p + 2 < deg) ? __expf(t) : 0.f;
            s0 += pe;
            #pragma unroll
            for (int i = 0; i < 2; ++i) {
                o0[2*i]   = fmaf(pe, (float)q.h[i][0], o0[2*i]);
                o0[2*i+1] = fmaf(pe, (float)q.h[i][1], o0[2*i+1]);
            }
        }
        {
            q.u = qa3;
            float t = 0.f;
            #pragma unroll
            for (int i = 0; i < 2; ++i) {
                h2 v2 = q.h[i] + rq.h[i];
                h2 lk = __builtin_elementwise_max(v2, v2 * c02);
                t = hdot2(lk, a2[i], t);
            }
            t = dpp_add_xor1(t); t = dpp_add_xor2(t);
            t += __shfl_xor(t, 4); t += __shfl_xor(t, 8);
            float pe = (p + 3 < deg) ? __expf(t) : 0.f;
            s1 += pe;
            #pragma unroll
            for (int i = 0; i < 2; ++i) {
                o1[2*i]   = fmaf(pe, (float)q.h[i][0], o1[2*i]);
                o1[2*i+1] = fmaf(pe, (float)q.h[i][1], o1[2*i+1]);
            }
        }
        qa0 = qb0; qa1 = qb1; qa2 = qb2; qa3 = qb3;
    }
    if (act) {
        float s = s0 + s1;
        float inv = 1.f / fmaxf(s, 1e-16f);
        float4 b4 = ((const float4*)bias)[j];
        float4 w;
        w.x = (o0[0] + o1[0]) * inv + b4.x;
        w.y = (o0[1] + o1[1]) * inv + b4.y;
        w.z = (o0[2] + o1[2]) * inv + b4.z;
        w.w = (o0[3] + o1[3]) * inv + b4.w;
        *(float4*)(outp + (size_t)nd * 40 + 4 * j) = w;
    }
}

extern "C" void kernel_launch(void* const* d_in, const int* in_sizes, int n_in,
                              void* d_out, int out_size, void* d_ws, size_t ws_size,
                              hipStream_t stream)
{
    const float* x    = (const float*)d_in[0];
    const int*   esrc = (const int*)d_in[1];
    const int*   edst = (const int*)d_in[2];
    const float* Wl0  = (const float*)d_in[3];
    const float* Wr0  = (const float*)d_in[4];
    const float* att0 = (const float*)d_in[5];
    const float* b0   = (const float*)d_in[6];
    const float* Wl1  = (const float*)d_in[7];
    const float* Wr1  = (const float*)d_in[8];
    const float* att1 = (const float*)d_in[9];
    const float* b1   = (const float*)d_in[10];
    const float* Wl2  = (const float*)d_in[11];
    const float* Wr2  = (const float*)d_in[12];
    const float* att2 = (const float*)d_in[13];
    const float* b2   = (const float*)d_in[14];
    float* out = (float*)d_out;

    const int N = in_sizes[0] / 128;   // 50000 (pack requires N <= 65536)
    const int E = in_sizes[1];         // 850000
    const int nbins = (N + 127) / 128; // 391

    char* ws = (char*)d_ws;
    size_t off = 0;
    auto walloc = [&](size_t bytes) -> void* {
        void* p = ws + off;
        off = (off + bytes + 255) & ~(size_t)255;
        return p;
    };
    __half*   xlh    = (__half*)walloc((size_t)N * 128 * 2);
    __half*   xrh    = (__half*)walloc((size_t)N * 128 * 2);
    __half*   hbuf   = (__half*)walloc((size_t)N * 128 * 2);
    __half*   Wt0    = (__half*)walloc(256 * 128 * 2);
    __half*   Wt1    = (__half*)walloc(256 * 128 * 2);
    __half*   Wt2    = (__half*)walloc(80 * 128 * 2);
    int*      binCnt = (int*)walloc((size_t)nbins * 4);
    unsigned* binned = (unsigned*)walloc((size_t)nbins * BINCAP * 4);
    int*      bucket = (int*)walloc((size_t)nbins * BSTRIDE * 4);
    int2*     meta   = (int2*)walloc((size_t)N * 8);
    int*      hist   = (int*)walloc(256 * 4);
    int*      dofs   = (int*)walloc(256 * 4);
    int*      perm   = (int*)walloc((size_t)N * 4);

    // ---- fp16 transposed weights ----
    wt_build<<<(2 * 256 * 128 + 80 * 128 + 255) / 256, 256, 0, stream>>>(
        Wl0, Wr0, Wl1, Wr1, Wl2, Wr2, Wt0, Wt1, Wt2);

    // ---- CSR build: bin then per-bin LDS CSR ----
    hipMemsetAsync(binCnt, 0, (size_t)nbins * 4, stream);
    hipMemsetAsync(hist, 0, 256 * 4, stream);
    bin_edges<<<256, 256, 0, stream>>>(esrc, edst, binCnt, binned, E, nbins);
    bin_to_csr<<<nbins, 256, 0, stream>>>(binCnt, binned, bucket, meta, N);

    // ---- degree-balanced node permutation (low-contention counting sort) ----
    deg_hist<<<PBLK, 256, 0, stream>>>(meta, hist, N);
    scan_hist<<<1, 256, 0, stream>>>(hist, dofs);
    perm_build<<<PBLK, 256, 0, stream>>>(meta, dofs, perm, N);

    int nblk = (N + 15) / 16;  // aggr: 16 nodes per 256-thread block (4/wave)
    int pblk = (N + 63) / 64;  // proj: 64 rows per block

    // ---- layer 0 ----
    proj_mfma<128, false><<<pblk, 256, 0, stream>>>(x, Wt0, xlh, xrh, N);
    aggr128<<<nblk, 256, 0, stream>>>(perm, meta, bucket, xlh, xrh, att0, b0, hbuf, N, 1);
    // ---- layer 1 ----
    proj_mfma<128, true><<<pblk, 256, 0, stream>>>(hbuf, Wt1, xlh, xrh, N);
    aggr128<<<nblk, 256, 0, stream>>>(perm, meta, bucket, xlh, xrh, att1, b1, hbuf, N, 1);
    // ---- layer 2 ----
    proj_mfma<40, true><<<pblk, 256, 0, stream>>>(hbuf, Wt2, xlh, xrh, N);
    aggr40<<<nblk, 256, 0, stream>>>(perm, meta, bucket, xlh, xrh, att2, b2, out, N);
}

// Round 14
// 182.377 us; speedup vs baseline: 1.8165x; 1.0725x over previous
//
#include <hip/hip_runtime.h>
#include <hip/hip_fp16.h>
#include <cmath>

typedef _Float16 half8 __attribute__((ext_vector_type(8)));
typedef _Float16 h2 __attribute__((ext_vector_type(2)));
typedef float f32x4 __attribute__((ext_vector_type(4)));

#define BINCAP 2600              // mean edges/bin ~2176, +9 sigma guard
#define BSTRIDE (BINCAP + 384)   // room for per-dst pad-to-4 (128 dst x 3)
#define NBINS_MAX 512            // N<=65536 (16-bit src pack also requires this)

// DPP cross-lane adds within quads (VALU pipe, no LDS): t += t[lane^mask]
__device__ __forceinline__ float dpp_add_xor1(float t) {
    int r = __builtin_amdgcn_update_dpp(0, __float_as_int(t), 0xB1, 0xF, 0xF, true);
    return t + __int_as_float(r);
}
__device__ __forceinline__ float dpp_add_xor2(float t) {
    int r = __builtin_amdgcn_update_dpp(0, __float_as_int(t), 0x4E, 0xF, 0xF, true);
    return t + __int_as_float(r);
}

__device__ __forceinline__ float hdot2(h2 a, h2 b, float acc) {
#if __has_builtin(__builtin_amdgcn_fdot2)
    return __builtin_amdgcn_fdot2(a, b, acc, false);
#else
    return acc + (float)a[0] * (float)b[0] + (float)a[1] * (float)b[1];
#endif
}

// ---------------- CSR build, phase 1: bin by dst>>7 (block-exclusive segments) ----------------
__global__ __launch_bounds__(256) void bin_edges(const int* __restrict__ src,
                                                 const int* __restrict__ dst,
                                                 int* __restrict__ binCnt,
                                                 unsigned* __restrict__ binned,
                                                 int E, int nbins)
{
    __shared__ int hist[NBINS_MAX];
    __shared__ int ofs[NBINS_MAX];
    int tid = threadIdx.x;
    for (int i = tid; i < nbins; i += 256) hist[i] = 0;
    __syncthreads();
    int chunk = (E + gridDim.x - 1) / gridDim.x;
    int e0 = blockIdx.x * chunk;
    int e1 = min(e0 + chunk, E);
    for (int e = e0 + tid; e < e1; e += 256)
        atomicAdd(&hist[dst[e] >> 7], 1);
    __syncthreads();
    for (int b = tid; b < nbins; b += 256) {
        int h = hist[b];
        ofs[b] = (h > 0) ? atomicAdd(&binCnt[b], h) : 0;
    }
    __syncthreads();
    for (int e = e0 + tid; e < e1; e += 256) {
        int d = dst[e];
        int b = d >> 7;
        int p = atomicAdd(&ofs[b], 1);
        if (p < BINCAP)
            binned[(size_t)b * BINCAP + p] = (unsigned)src[e] | ((unsigned)(d & 127) << 16);
    }
}

// ---------------- CSR build, phase 2: per-bin exact CSR via LDS, coalesced flush ----------------
__global__ __launch_bounds__(256) void bin_to_csr(const int* __restrict__ binCnt,
                                                  const unsigned* __restrict__ binned,
                                                  int* __restrict__ bucket,
                                                  int2* __restrict__ meta, int N)
{
    __shared__ int dcnt[128], ps[128], dpos[128];
    __shared__ int sbuf[BSTRIDE];
    __shared__ int tot_s;
    int b = blockIdx.x, tid = threadIdx.x;
    int nb = min(binCnt[b], BINCAP);
    size_t inbase = (size_t)b * BINCAP;
    size_t outbase = (size_t)b * BSTRIDE;
    if (tid < 128) dcnt[tid] = 0;
    __syncthreads();
    for (int i = tid; i < nb; i += 256)
        atomicAdd(&dcnt[(binned[inbase + i] >> 16) & 127], 1);
    __syncthreads();
    int pc = 0;
    if (tid < 128) { pc = (dcnt[tid] + 3) & ~3; ps[tid] = pc; }
    __syncthreads();
    for (int o = 1; o < 128; o <<= 1) {
        int v = (tid < 128 && tid >= o) ? ps[tid - o] : 0;
        __syncthreads();
        if (tid < 128) ps[tid] += v;
        __syncthreads();
    }
    if (tid < 128) {
        int dofs = ps[tid] - pc;
        dpos[tid] = dofs;
        for (int k = dcnt[tid]; k < pc; ++k) sbuf[dofs + k] = 0;   // zero pad slots
        int gd = b * 128 + tid;
        if (gd < N) meta[gd] = make_int2((int)outbase + dofs, dcnt[tid]);
        if (tid == 127) tot_s = ps[127];
    }
    __syncthreads();
    for (int i = tid; i < nb; i += 256) {
        unsigned u = binned[inbase + i];
        int p = atomicAdd(&dpos[(u >> 16) & 127], 1);
        sbuf[p] = (int)(u & 0xFFFFu);
    }
    __syncthreads();
    int tot = min(tot_s, BSTRIDE);
    for (int i = tid; i < tot; i += 256)
        bucket[outbase + i] = sbuf[i];
}

// ---------------- Wt build: fp16 transposed weights Wt[c][k] = W[k][c] ----------------
__global__ void wt_build(const float* __restrict__ Wl0, const float* __restrict__ Wr0,
                         const float* __restrict__ Wl1, const float* __restrict__ Wr1,
                         const float* __restrict__ Wl2, const float* __restrict__ Wr2,
                         __half* __restrict__ Wt0, __half* __restrict__ Wt1,
                         __half* __restrict__ Wt2) {
    int i = blockIdx.x * blockDim.x + threadIdx.x;
    const int T01 = 256 * 128, T2 = 80 * 128;
    if (i < T01) {
        int c = i >> 7, k = i & 127;
        float v = (c < 128) ? Wl0[k * 128 + c] : Wr0[k * 128 + (c - 128)];
        Wt0[i] = __float2half(v);
    } else if (i < 2 * T01) {
        int j = i - T01;
        int c = j >> 7, k = j & 127;
        float v = (c < 128) ? Wl1[k * 128 + c] : Wr1[k * 128 + (c - 128)];
        Wt1[j] = __float2half(v);
    } else if (i < 2 * T01 + T2) {
        int j = i - 2 * T01;
        int c = j >> 7, k = j & 127;
        float v = (c < 40) ? Wl2[k * 40 + c] : Wr2[k * 40 + (c - 40)];
        Wt2[j] = __float2half(v);
    }
}

// ---------------- MFMA projection (input fp32 or fp16 via HIN) ----------------
template<int OUTH, bool HIN>
__global__ __launch_bounds__(256) void proj_mfma(const void* __restrict__ xin,
                                                 const __half* __restrict__ Wt,
                                                 __half* __restrict__ xl,
                                                 __half* __restrict__ xr,
                                                 int n)
{
    constexpr int OUTT = 2 * OUTH;
    constexpr int CT = OUTT / 16;
    __shared__ uint4 lds[1024 + OUTT * 16];
    int t = threadIdx.x;
    int r0 = blockIdx.x * 64;
    {
        int row = t >> 2;
        int k0 = (t & 3) * 32;
        int gr = r0 + row;
        #pragma unroll
        for (int s = 0; s < 4; ++s) {
            union { uint4 u; _Float16 h[8]; } pk;
            if (gr < n) {
                if constexpr (HIN) {
                    const uint4* xp = (const uint4*)((const __half*)xin + (size_t)gr * 128 + k0);
                    pk.u = xp[s];
                } else {
                    const float4* xp = (const float4*)((const float*)xin + (size_t)gr * 128 + k0 + s * 8);
                    float4 f0 = xp[0], f1 = xp[1];
                    pk.h[0] = (_Float16)f0.x; pk.h[1] = (_Float16)f0.y;
                    pk.h[2] = (_Float16)f0.z; pk.h[3] = (_Float16)f0.w;
                    pk.h[4] = (_Float16)f1.x; pk.h[5] = (_Float16)f1.y;
                    pk.h[6] = (_Float16)f1.z; pk.h[7] = (_Float16)f1.w;
                }
            } else {
                pk.u = make_uint4(0, 0, 0, 0);
            }
            int j = (t & 3) * 4 + s;
            lds[row * 16 + (j ^ (row & 7))] = pk.u;
        }
    }
    {
        const uint4* Wtv = (const uint4*)Wt;
        for (int m = t; m < OUTT * 16; m += 256) {
            int c = m >> 4, j = m & 15;
            lds[1024 + c * 16 + (j ^ (c & 7))] = Wtv[m];
        }
    }
    __syncthreads();
    int w = t >> 6, l = t & 63;
    int lr = l & 15, lg = l >> 4;
    half8 af[4];
    {
        int row = w * 16 + lr;
        #pragma unroll
        for (int kb = 0; kb < 4; ++kb) {
            int j = kb * 4 + lg;
            af[kb] = *reinterpret_cast<const half8*>(&lds[row * 16 + (j ^ (row & 7))]);
        }
    }
    f32x4 acc[CT];
    #pragma unroll
    for (int ct = 0; ct < CT; ++ct) acc[ct] = (f32x4){0.f, 0.f, 0.f, 0.f};
    int csw = lr & 7;
    #pragma unroll
    for (int ct = 0; ct < CT; ++ct) {
        int c = ct * 16 + lr;
        #pragma unroll
        for (int kb = 0; kb < 4; ++kb) {
            int j = kb * 4 + lg;
            half8 bf = *reinterpret_cast<const half8*>(&lds[1024 + c * 16 + (j ^ csw)]);
            acc[ct] = __builtin_amdgcn_mfma_f32_16x16x32_f16(af[kb], bf, acc[ct], 0, 0, 0);
        }
    }
    #pragma unroll
    for (int ct = 0; ct < CT; ++ct) {
        int c = ct * 16 + lr;
        #pragma unroll
        for (int i = 0; i < 4; ++i) {
            int gr = r0 + w * 16 + lg * 4 + i;
            if (gr < n) {
                __half h = __float2half(acc[ct][i]);
                if (c < OUTH) xl[(size_t)gr * OUTH + c] = h;
                else          xr[(size_t)gr * OUTH + (c - OUTH)] = h;
            }
        }
    }
}

// ---------------- fused per-node GATv2, HC=128: one node per 16-lane group ----------------
// no-max softmax (logits bounded << 88), 4-deep unroll, 4 independent states,
// fma accumulation straight from fp16 halves. (R10 structure — no prefetch/perm:
// occupancy, not ILP, does the latency hiding here; R11/R12 proved the converse.)
__global__ void aggr128(const int2* __restrict__ meta, const int* __restrict__ bucket,
                        const __half* __restrict__ xlh, const __half* __restrict__ xrh,
                        const float* __restrict__ att, const float* __restrict__ bias,
                        __half* __restrict__ outp, int N, int do_relu)
{
    int wave = threadIdx.x >> 6;
    int lane = threadIdx.x & 63;
    int grp = lane >> 4;
    int j = lane & 15;
    int nd = (blockIdx.x * (blockDim.x >> 6) + wave) * 4 + grp;
    if (nd >= N) return;
    union { uint4 u; h2 h[4]; } rq;
    rq.u = ((const uint4*)xrh)[(size_t)nd * 16 + j];
    h2 a2[4];
    {
        float4 t0 = ((const float4*)att)[2 * j];
        float4 t1 = ((const float4*)att)[2 * j + 1];
        a2[0] = h2{(_Float16)t0.x, (_Float16)t0.y};
        a2[1] = h2{(_Float16)t0.z, (_Float16)t0.w};
        a2[2] = h2{(_Float16)t1.x, (_Float16)t1.y};
        a2[3] = h2{(_Float16)t1.z, (_Float16)t1.w};
    }
    const uint4* xlv = (const uint4*)xlh;
    int2 md = meta[nd];
    int beg = md.x, deg = md.y;
    const int* brow = bucket + beg;
    const h2 c02 = h2{(_Float16)0.2f, (_Float16)0.2f};
    float s0 = 0.f, s1 = 0.f, s2 = 0.f, s3 = 0.f;
    float o0[8], o1[8], o2[8], o3[8];
    #pragma unroll
    for (int i = 0; i < 8; ++i) { o0[i] = 0.f; o1[i] = 0.f; o2[i] = 0.f; o3[i] = 0.f; }
    for (int p = 0; p < deg; p += 4) {
        int4 ss = *(const int4*)(brow + p);     // beg 4-aligned; pads are node 0
        union { uint4 u; h2 h[4]; } q0, q1, q2, q3;
        q0.u = xlv[(size_t)ss.x * 16 + j];
        q1.u = xlv[(size_t)ss.y * 16 + j];
        q2.u = xlv[(size_t)ss.z * 16 + j];
        q3.u = xlv[(size_t)ss.w * 16 + j];
        {
            float t = 0.f;
            #pragma unroll
            for (int i = 0; i < 4; ++i) {
                h2 v2 = q0.h[i] + rq.h[i];
                h2 lk = __builtin_elementwise_max(v2, v2 * c02);
                t = hdot2(lk, a2[i], t);
            }
            t = dpp_add_xor1(t);
            float pe = __expf(t);               // slot 0 always valid (p < deg)
            s0 += pe;
            #pragma unroll
            for (int i = 0; i < 4; ++i) {
                o0[2*i]   = fmaf(pe, (float)q0.h[i][0], o0[2*i]);
                o0[2*i+1] = fmaf(pe, (float)q0.h[i][1], o0[2*i+1]);
            }
        }
        {
            float t = 0.f;
            #pragma unroll
            for (int i = 0; i < 4; ++i) {
                h2 v2 = q1.h[i] + rq.h[i];
                h2 lk = __builtin_elementwise_max(v2, v2 * c02);
                t = hdot2(lk, a2[i], t);
            }
            t = dpp_add_xor1(t);
            float pe = (p + 1 < deg) ? __expf(t) : 0.f;
            s1 += pe;
            #pragma unroll
            for (int i = 0; i < 4; ++i) {
                o1[2*i]   = fmaf(pe, (float)q1.h[i][0], o1[2*i]);
                o1[2*i+1] = fmaf(pe, (float)q1.h[i][1], o1[2*i+1]);
            }
        }
        {
            float t = 0.f;
            #pragma unroll
            for (int i = 0; i < 4; ++i) {
                h2 v2 = q2.h[i] + rq.h[i];
                h2 lk = __builtin_elementwise_max(v2, v2 * c02);
                t = hdot2(lk, a2[i], t);
            }
            t = dpp_add_xor1(t);
            float pe = (p + 2 < deg) ? __expf(t) : 0.f;
            s2 += pe;
            #pragma unroll
            for (int i = 0; i < 4; ++i) {
                o2[2*i]   = fmaf(pe, (float)q2.h[i][0], o2[2*i]);
                o2[2*i+1] = fmaf(pe, (float)q2.h[i][1], o2[2*i+1]);
            }
        }
        {
            float t = 0.f;
            #pragma unroll
            for (int i = 0; i < 4; ++i) {
                h2 v2 = q3.h[i] + rq.h[i];
                h2 lk = __builtin_elementwise_max(v2, v2 * c02);
                t = hdot2(lk, a2[i], t);
            }
            t = dpp_add_xor1(t);
            float pe = (p + 3 < deg) ? __expf(t) : 0.f;
            s3 += pe;
            #pragma unroll
            for (int i = 0; i < 4; ++i) {
                o3[2*i]   = fmaf(pe, (float)q3.h[i][0], o3[2*i]);
                o3[2*i+1] = fmaf(pe, (float)q3.h[i][1], o3[2*i+1]);
            }
        }
    }
    float s = (s0 + s1) + (s2 + s3);
    {
        float inv = 1.f / fmaxf(s, 1e-16f);
        float4 b0 = ((const float4*)bias)[2 * j];
        float4 b1 = ((const float4*)bias)[2 * j + 1];
        float w[8];
        #pragma unroll
        for (int i = 0; i < 8; ++i)
            w[i] = ((o0[i] + o1[i]) + (o2[i] + o3[i])) * inv;
        w[0] += b0.x; w[1] += b0.y; w[2] += b0.z; w[3] += b0.w;
        w[4] += b1.x; w[5] += b1.y; w[6] += b1.z; w[7] += b1.w;
        if (do_relu) {
            #pragma unroll
            for (int i = 0; i < 8; ++i) w[i] = fmaxf(w[i], 0.f);
        }
        union { uint4 u; __half2 h[4]; } ow;
        ow.h[0] = __floats2half2_rn(w[0], w[1]);
        ow.h[1] = __floats2half2_rn(w[2], w[3]);
        ow.h[2] = __floats2half2_rn(w[4], w[5]);
        ow.h[3] = __floats2half2_rn(w[6], w[7]);
        ((uint4*)outp)[(size_t)nd * 16 + j] = ow.u;
    }
}

// ---------------- fused per-node pipeline, HC=40: one node per 16-lane group, fp32 out ----------------
__global__ void aggr40(const int2* __restrict__ meta, const int* __restrict__ bucket,
                       const __half* __restrict__ xlh, const __half* __restrict__ xrh,
                       const float* __restrict__ att, const float* __restrict__ bias,
                       float* __restrict__ outp, int N)
{
    int wave = threadIdx.x >> 6;
    int lane = threadIdx.x & 63;
    int grp = lane >> 4;
    int j = lane & 15;
    int nd = (blockIdx.x * (blockDim.x >> 6) + wave) * 4 + grp;
    if (nd >= N) return;
    bool act = (j < 10);
    union { uint2 u; h2 h[2]; } rq;
    rq.u = make_uint2(0, 0);
    h2 a2[2] = {h2{(_Float16)0.f, (_Float16)0.f}, h2{(_Float16)0.f, (_Float16)0.f}};
    if (act) {
        rq.u = *(const uint2*)(xrh + (size_t)nd * 40 + 4 * j);
        float4 a4 = ((const float4*)att)[j];
        a2[0] = h2{(_Float16)a4.x, (_Float16)a4.y};
        a2[1] = h2{(_Float16)a4.z, (_Float16)a4.w};
    }
    int2 md = meta[nd];
    int beg = md.x, deg = md.y;
    const int* brow = bucket + beg;
    const h2 c02 = h2{(_Float16)0.2f, (_Float16)0.2f};
    float s0 = 0.f, s1 = 0.f;
    float o0[4], o1[4];
    #pragma unroll
    for (int i = 0; i < 4; ++i) { o0[i] = 0.f; o1[i] = 0.f; }
    for (int p = 0; p < deg; p += 4) {
        int4 ss = *(const int4*)(brow + p);
        union { uint2 u; h2 h[2]; } q0, q1, q2, q3;
        q0.u = act ? *(const uint2*)(xlh + (size_t)ss.x * 40 + 4 * j) : make_uint2(0, 0);
        q1.u = act ? *(const uint2*)(xlh + (size_t)ss.y * 40 + 4 * j) : make_uint2(0, 0);
        q2.u = act ? *(const uint2*)(xlh + (size_t)ss.z * 40 + 4 * j) : make_uint2(0, 0);
        q3.u = act ? *(const uint2*)(xlh + (size_t)ss.w * 40 + 4 * j) : make_uint2(0, 0);
        {
            float t = 0.f;
            #pragma unroll
            for (int i = 0; i < 2; ++i) {
                h2 v2 = q0.h[i] + rq.h[i];
                h2 lk = __builtin_elementwise_max(v2, v2 * c02);
                t = hdot2(lk, a2[i], t);
            }
            t = dpp_add_xor1(t); t = dpp_add_xor2(t);
            t += __shfl_xor(t, 4); t += __shfl_xor(t, 8);
            float pe = __expf(t);
            s0 += pe;
            #pragma unroll
            for (int i = 0; i < 2; ++i) {
                o0[2*i]   = fmaf(pe, (float)q0.h[i][0], o0[2*i]);
                o0[2*i+1] = fmaf(pe, (float)q0.h[i][1], o0[2*i+1]);
            }
        }
        {
            float t = 0.f;
            #pragma unroll
            for (int i = 0; i < 2; ++i) {
                h2 v2 = q1.h[i] + rq.h[i];
                h2 lk = __builtin_elementwise_max(v2, v2 * c02);
                t = hdot2(lk, a2[i], t);
            }
            t = dpp_add_xor1(t); t = dpp_add_xor2(t);
            t += __shfl_xor(t, 4); t += __shfl_xor(t, 8);
            float pe = (p + 1 < deg) ? __expf(t) : 0.f;
            s1 += pe;
            #pragma unroll
            for (int i = 0; i < 2; ++i) {
                o1[2*i]   = fmaf(pe, (float)q1.h[i][0], o1[2*i]);
                o1[2*i+1] = fmaf(pe, (float)q1.h[i][1], o1[2*i+1]);
            }
        }
        {
            float t = 0.f;
            #pragma unroll
            for (int i = 0; i < 2; ++i) {
                h2 v2 = q2.h[i] + rq.h[i];
                h2 lk = __builtin_elementwise_max(v2, v2 * c02);
                t = hdot2(lk, a2[i], t);
            }
            t = dpp_add_xor1(t); t = dpp_add_xor2(t);
            t += __shfl_xor(t, 4); t += __shfl_xor(t, 8);
            float pe = (p + 2 < deg) ? __expf(t) : 0.f;
            s0 += pe;
            #pragma unroll
            for (int i = 0; i < 2; ++i) {
                o0[2*i]   = fmaf(pe, (float)q2.h[i][0], o0[2*i]);
                o0[2*i+1] = fmaf(pe, (float)q2.h[i][1], o0[2*i+1]);
            }
        }
        {
            float t = 0.f;
            #pragma unroll
            for (int i = 0; i < 2; ++i) {
                h2 v2 = q3.h[i] + rq.h[i];
                h2 lk = __builtin_elementwise_max(v2, v2 * c02);
                t = hdot2(lk, a2[i], t);
            }
            t = dpp_add_xor1(t); t = dpp_add_xor2(t);
            t += __shfl_xor(t, 4); t += __shfl_xor(t, 8);
            float pe = (p + 3 < deg) ? __expf(t) : 0.f;
            s1 += pe;
            #pragma unroll
            for (int i = 0; i < 2; ++i) {
                o1[2*i]   = fmaf(pe, (float)q3.h[i][0], o1[2*i]);
                o1[2*i+1] = fmaf(pe, (float)q3.h[i][1], o1[2*i+1]);
            }
        }
    }
    if (act) {
        float s = s0 + s1;
        float inv = 1.f / fmaxf(s, 1e-16f);
        float4 b4 = ((const float4*)bias)[j];
        float4 w;
        w.x = (o0[0] + o1[0]) * inv + b4.x;
        w.y = (o0[1] + o1[1]) * inv + b4.y;
        w.z = (o0[2] + o1[2]) * inv + b4.z;
        w.w = (o0[3] + o1[3]) * inv + b4.w;
        *(float4*)(outp + (size_t)nd * 40 + 4 * j) = w;
    }
}

extern "C" void kernel_launch(void* const* d_in, const int* in_sizes, int n_in,
                              void* d_out, int out_size, void* d_ws, size_t ws_size,
                              hipStream_t stream)
{
    const float* x    = (const float*)d_in[0];
    const int*   esrc = (const int*)d_in[1];
    const int*   edst = (const int*)d_in[2];
    const float* Wl0  = (const float*)d_in[3];
    const float* Wr0  = (const float*)d_in[4];
    const float* att0 = (const float*)d_in[5];
    const float* b0   = (const float*)d_in[6];
    const float* Wl1  = (const float*)d_in[7];
    const float* Wr1  = (const float*)d_in[8];
    const float* att1 = (const float*)d_in[9];
    const float* b1   = (const float*)d_in[10];
    const float* Wl2  = (const float*)d_in[11];
    const float* Wr2  = (const float*)d_in[12];
    const float* att2 = (const float*)d_in[13];
    const float* b2   = (const float*)d_in[14];
    float* out = (float*)d_out;

    const int N = in_sizes[0] / 128;   // 50000 (pack requires N <= 65536)
    const int E = in_sizes[1];         // 850000
    const int nbins = (N + 127) / 128; // 391

    char* ws = (char*)d_ws;
    size_t off = 0;
    auto walloc = [&](size_t bytes) -> void* {
        void* p = ws + off;
        off = (off + bytes + 255) & ~(size_t)255;
        return p;
    };
    __half*   xlh    = (__half*)walloc((size_t)N * 128 * 2);
    __half*   xrh    = (__half*)walloc((size_t)N * 128 * 2);
    __half*   hbuf   = (__half*)walloc((size_t)N * 128 * 2);
    __half*   Wt0    = (__half*)walloc(256 * 128 * 2);
    __half*   Wt1    = (__half*)walloc(256 * 128 * 2);
    __half*   Wt2    = (__half*)walloc(80 * 128 * 2);
    int*      binCnt = (int*)walloc((size_t)nbins * 4);
    unsigned* binned = (unsigned*)walloc((size_t)nbins * BINCAP * 4);
    int*      bucket = (int*)walloc((size_t)nbins * BSTRIDE * 4);
    int2*     meta   = (int2*)walloc((size_t)N * 8);

    // ---- fp16 transposed weights ----
    wt_build<<<(2 * 256 * 128 + 80 * 128 + 255) / 256, 256, 0, stream>>>(
        Wl0, Wr0, Wl1, Wr1, Wl2, Wr2, Wt0, Wt1, Wt2);

    // ---- CSR build: bin (block-exclusive segments) then per-bin LDS CSR ----
    hipMemsetAsync(binCnt, 0, (size_t)nbins * 4, stream);
    bin_edges<<<256, 256, 0, stream>>>(esrc, edst, binCnt, binned, E, nbins);
    bin_to_csr<<<nbins, 256, 0, stream>>>(binCnt, binned, bucket, meta, N);

    int nblk = (N + 15) / 16;  // aggr: 16 nodes per 256-thread block (4/wave)
    int pblk = (N + 63) / 64;  // proj: 64 rows per block

    // ---- layer 0 ----
    proj_mfma<128, false><<<pblk, 256, 0, stream>>>(x, Wt0, xlh, xrh, N);
    aggr128<<<nblk, 256, 0, stream>>>(meta, bucket, xlh, xrh, att0, b0, hbuf, N, 1);
    // ---- layer 1 ----
    proj_mfma<128, true><<<pblk, 256, 0, stream>>>(hbuf, Wt1, xlh, xrh, N);
    aggr128<<<nblk, 256, 0, stream>>>(meta, bucket, xlh, xrh, att1, b1, hbuf, N, 1);
    // ---- layer 2 ----
    proj_mfma<40, true><<<pblk, 256, 0, stream>>>(hbuf, Wt2, xlh, xrh, N);
    aggr40<<<nblk, 256, 0, stream>>>(meta, bucket, xlh, xrh, att2, b2, out, N);
}